// Round 3
// baseline (112.841 us; speedup 1.0000x reference)
//
#include <hip/hip_runtime.h>
#include <hip/hip_bf16.h>

typedef __bf16 bf16x8 __attribute__((ext_vector_type(8)));
typedef float f32x4 __attribute__((ext_vector_type(4)));
typedef unsigned int u32;

#define B_SZ 64
#define L_SZ 1024
#define D_SZ 512

// ws layout (bytes):
//   [0,        524288)  Wt    : bf16 W_enc^T  [N=512][K=512]
//   [524288,   655360)  bias2p: f32 [64][512]  (attn2 + b_dec + b_enc)
//   [655360,   917504)  logits: f32 [64][1024]
//   [917504,  1966080)  part  : f32 [64][8][512]
#define WS_WT     0
#define WS_BIAS   524288
#define WS_LOGITS 655360
#define WS_PART   917504

__device__ __forceinline__ unsigned short f2bf(float f) {
    __bf16 h = (__bf16)f;
    return __builtin_bit_cast(unsigned short, h);
}

__device__ __forceinline__ void gload_lds16(const void* g, void* l) {
    __builtin_amdgcn_global_load_lds(
        (const __attribute__((address_space(1))) u32*)g,
        (__attribute__((address_space(3))) u32*)l, 16, 0, 0);
}

// K0a: Wt[n][k] = bf16(W_enc[k][n])
__global__ void k_wt(const float* __restrict__ W, unsigned short* __restrict__ Wt) {
    int n = blockIdx.x;
    for (int k = threadIdx.x; k < 512; k += 256)
        Wt[n * 512 + k] = f2bf(W[k * 512 + n]);
}

// K0b: bias2p[b][n] = dec[b]·W_dec[:,n] + b_dec[n] + b_enc[n]
__global__ void k_bias2(const float* __restrict__ dec, const float* __restrict__ Wd,
                        const float* __restrict__ b_dec, const float* __restrict__ b_enc,
                        float* __restrict__ bias2p) {
    int blk = blockIdx.x;           // 256 blocks: b = blk>>2, nc = blk&3
    int b = blk >> 2, nc = blk & 3;
    int t = threadIdx.x;
    __shared__ float sdec[512];
    __shared__ float red[256];
    for (int k = t; k < 512; k += 256) sdec[k] = dec[b * 512 + k];
    __syncthreads();
    int n = nc * 128 + (t & 127);
    int kh = t >> 7;                // 0 or 1
    float acc = 0.f;
    int k0 = kh * 256;
    #pragma unroll 4
    for (int k = k0; k < k0 + 256; ++k)
        acc += sdec[k] * Wd[k * 512 + n];
    red[t] = acc;
    __syncthreads();
    if (t < 128) {
        int nn = nc * 128 + t;
        bias2p[b * 512 + nn] = red[t] + red[t + 128] + b_dec[nn] + b_enc[nn];
    }
}

// K1: fused enc@W_enc + bias -> relu -> ·W_full  =>  logits [B,L]
// 512 blocks x 512 thr (8 waves). Block = 128 rows. Wave (rg, h): rg = row
// group (32 rows, M_rep=2), h = K-half (256). A in regs (64 VGPR, spill-free);
// wave-pair combines partial acc via LDS (b128, conflict-free) before relu.
__global__ __launch_bounds__(512, 4) void k_logits(
        const float* __restrict__ enc, const unsigned short* __restrict__ Wt,
        const float* __restrict__ bias2p, const float* __restrict__ Wf,
        const float* __restrict__ bfull, float* __restrict__ logits) {
    __shared__ __align__(16) unsigned short lds[2][8192];  // 2 x 16 KB (16 cols x 512 K)
    __shared__ f32x4 comb[4][2][64];                       // 8 KB partial-acc exchange

    int t = threadIdx.x;
    int lane = t & 63;
    int w = t >> 6;                 // wave 0..7
    int rg = w >> 1;                // row group 0..3
    int h = w & 1;                  // K-half
    int blk = blockIdx.x;           // 512 blocks of 128 rows
    int b = blk >> 3;               // 8 blocks per batch
    int m = lane & 15;              // A row within tile / D col
    int g = lane >> 4;              // k sub-group 0..3

    // stage chunk nc_ into lds[bufi]: wave w stages cols w*2, w*2+1 (1 KB each).
    // LDS dest linear (wave-uniform base + lane*16); global src pre-swizzled u^c.
    #define STAGE(bufi, nc_)                                                      \
        {                                                                         \
            int n0_ = (nc_) * 16;                                                 \
            _Pragma("unroll")                                                     \
            for (int j = 0; j < 2; ++j) {                                         \
                int c_ = w * 2 + j;                                               \
                const char* src_ = (const char*)Wt + (size_t)(n0_ + c_) * 1024    \
                                   + ((lane ^ c_) << 4);                          \
                gload_lds16(src_, (char*)&lds[bufi][0] + c_ * 1024);              \
            }                                                                     \
        }

    STAGE(0, 0)

    // A frags: rows blk*128 + rg*32 + {m, 16+m}, k in [h*256, h*256+256)
    bf16x8 A0[8], A1[8];
    {
        const float* ap0 = enc + (size_t)(blk * 128 + rg * 32 + m) * 512 + h * 256 + g * 8;
        const float* ap1 = ap0 + 16 * 512;
        #pragma unroll
        for (int f = 0; f < 8; ++f) {
            float4 x = *(const float4*)(ap0 + f * 32);
            float4 y = *(const float4*)(ap0 + f * 32 + 4);
            bf16x8 a;
            a[0] = (__bf16)x.x; a[1] = (__bf16)x.y; a[2] = (__bf16)x.z; a[3] = (__bf16)x.w;
            a[4] = (__bf16)y.x; a[5] = (__bf16)y.y; a[6] = (__bf16)y.z; a[7] = (__bf16)y.w;
            A0[f] = a;
            float4 x1 = *(const float4*)(ap1 + f * 32);
            float4 y1 = *(const float4*)(ap1 + f * 32 + 4);
            bf16x8 a1;
            a1[0] = (__bf16)x1.x; a1[1] = (__bf16)x1.y; a1[2] = (__bf16)x1.z; a1[3] = (__bf16)x1.w;
            a1[4] = (__bf16)y1.x; a1[5] = (__bf16)y1.y; a1[6] = (__bf16)y1.z; a1[7] = (__bf16)y1.w;
            A1[f] = a1;
        }
    }

    __syncthreads();                // chunk 0 staged; A loaded

    float p0[4] = {0.f, 0.f, 0.f, 0.f};
    float p1[4] = {0.f, 0.f, 0.f, 0.f};
    int swz = m << 4;

    for (int nc = 0; nc < 32; ++nc) {
        int buf = nc & 1;
        if (nc < 31) {
            if (buf) STAGE(0, nc + 1) else STAGE(1, nc + 1)
        }
        const char* base = (const char*)&lds[buf][0] + m * 1024;
        f32x4 acc0 = {0.f, 0.f, 0.f, 0.f};
        f32x4 acc1 = {0.f, 0.f, 0.f, 0.f};
        #pragma unroll
        for (int f = 0; f < 8; ++f) {
            uint4 raw = *(const uint4*)(base + (((h * 8 + f) * 64 + g * 16) ^ swz));
            bf16x8 bfr = __builtin_bit_cast(bf16x8, raw);
            acc0 = __builtin_amdgcn_mfma_f32_16x16x32_bf16(A0[f], bfr, acc0, 0, 0, 0);
            acc1 = __builtin_amdgcn_mfma_f32_16x16x32_bf16(A1[f], bfr, acc1, 0, 0, 0);
        }
        if (h == 1) {
            comb[rg][0][lane] = acc0;
            comb[rg][1][lane] = acc1;
        }
        __syncthreads();            // comb visible; stage(nc+1) also drained here or next
        if (h == 0) {
            f32x4 c0 = comb[rg][0][lane];
            f32x4 c1 = comb[rg][1][lane];
            int col = nc * 16 + m;
            float bias = bias2p[b * 512 + col];
            float wf = Wf[col];
            #pragma unroll
            for (int r = 0; r < 4; ++r) {
                float v0 = acc0[r] + c0[r] + bias; v0 = v0 > 0.f ? v0 : 0.f; p0[r] += v0 * wf;
                float v1 = acc1[r] + c1[r] + bias; v1 = v1 > 0.f ? v1 : 0.f; p1[r] += v1 * wf;
            }
        }
        __syncthreads();            // comb reads done; staged buf ready for next iter
    }

    // h0 waves: reduce over the 16 cols (lanes varying in m, same g)
    if (h == 0) {
        float bf0 = bfull[0];
        int rowbase = blk * 128 + rg * 32;
        #pragma unroll
        for (int r = 0; r < 4; ++r) {
            float v = p0[r];
            v += __shfl_xor(v, 1, 64);
            v += __shfl_xor(v, 2, 64);
            v += __shfl_xor(v, 4, 64);
            v += __shfl_xor(v, 8, 64);
            if (m == 0) logits[rowbase + g * 4 + r] = v + bf0;
            float u = p1[r];
            u += __shfl_xor(u, 1, 64);
            u += __shfl_xor(u, 2, 64);
            u += __shfl_xor(u, 4, 64);
            u += __shfl_xor(u, 8, 64);
            if (m == 0) logits[rowbase + 16 + g * 4 + r] = u + bf0;
        }
    }
}

// K2: softmax over L per batch; writes alpha straight into d_out region
__global__ void k_softmax(const float* __restrict__ logits, float* __restrict__ alpha) {
    int b = blockIdx.x;
    int t = threadIdx.x;
    __shared__ float red[256];
    float4 v = ((const float4*)(logits + b * 1024))[t];
    float mx = fmaxf(fmaxf(v.x, v.y), fmaxf(v.z, v.w));
    red[t] = mx;
    __syncthreads();
    for (int s = 128; s > 0; s >>= 1) {
        if (t < s) red[t] = fmaxf(red[t], red[t + s]);
        __syncthreads();
    }
    mx = red[0];
    __syncthreads();
    float4 e;
    e.x = expf(v.x - mx); e.y = expf(v.y - mx);
    e.z = expf(v.z - mx); e.w = expf(v.w - mx);
    red[t] = e.x + e.y + e.z + e.w;
    __syncthreads();
    for (int s = 128; s > 0; s >>= 1) {
        if (t < s) red[t] += red[t + s];
        __syncthreads();
    }
    float inv = 1.0f / red[0];
    float4 o;
    o.x = e.x * inv; o.y = e.y * inv; o.z = e.z * inv; o.w = e.w * inv;
    ((float4*)(alpha + b * 1024))[t] = o;
}

// K3: partial weighted sums over l-chunks of 128 (float4 loads, 16B/lane)
__global__ void k_wsum_part(const float* __restrict__ enc, const float* __restrict__ alpha,
                            float* __restrict__ part) {
    int blk = blockIdx.x;           // 512 blocks: b = blk>>3, chunk c = blk&7
    int b = blk >> 3, c = blk & 7;
    int t = threadIdx.x;
    int col = (t & 127) * 4;
    int lh = t >> 7;                // 0/1: which l-parity
    const float* ep = enc + (size_t)(b * 1024 + c * 128) * 512;
    const float* al = alpha + b * 1024 + c * 128;
    float4 s = {0.f, 0.f, 0.f, 0.f};
    #pragma unroll 4
    for (int i = 0; i < 64; ++i) {
        int l = i * 2 + lh;
        float a = al[l];
        float4 e = *(const float4*)(ep + (size_t)l * 512 + col);
        s.x += e.x * a; s.y += e.y * a; s.z += e.z * a; s.w += e.w * a;
    }
    __shared__ float red[2][512];
    *(float4*)&red[lh][col] = s;
    __syncthreads();
    if (t < 128) {
        float4 a0 = *(const float4*)&red[0][t * 4];
        float4 a1 = *(const float4*)&red[1][t * 4];
        float4 o;
        o.x = a0.x + a1.x; o.y = a0.y + a1.y;
        o.z = a0.z + a1.z; o.w = a0.w + a1.w;
        *(float4*)(part + (size_t)blk * 512 + t * 4) = o;
    }
}

// K4: reduce 8 partials -> attn_weighted_enc (128 thr, float4)
__global__ void k_wsum_final(const float* __restrict__ part, float* __restrict__ out) {
    int b = blockIdx.x;
    int t = threadIdx.x;
    float4 s = {0.f, 0.f, 0.f, 0.f};
    #pragma unroll
    for (int c = 0; c < 8; ++c) {
        float4 v = *(const float4*)(part + (size_t)(b * 8 + c) * 512 + t * 4);
        s.x += v.x; s.y += v.y; s.z += v.z; s.w += v.w;
    }
    *(float4*)(out + b * 512 + t * 4) = s;
}

extern "C" void kernel_launch(void* const* d_in, const int* in_sizes, int n_in,
                              void* d_out, int out_size, void* d_ws, size_t ws_size,
                              hipStream_t stream) {
    const float* enc    = (const float*)d_in[0];  // [64,1024,512]
    const float* dec    = (const float*)d_in[1];  // [64,512]
    const float* W_enc  = (const float*)d_in[2];  // [512,512]
    const float* b_enc  = (const float*)d_in[3];  // [512]
    const float* W_dec  = (const float*)d_in[4];  // [512,512]
    const float* b_dec  = (const float*)d_in[5];  // [512]
    const float* W_full = (const float*)d_in[6];  // [512]
    const float* b_full = (const float*)d_in[7];  // scalar

    float* out = (float*)d_out;                   // [0,32768) weighted enc; [32768,98304) alpha
    char* ws = (char*)d_ws;
    unsigned short* Wt = (unsigned short*)(ws + WS_WT);
    float* bias2p = (float*)(ws + WS_BIAS);
    float* logits = (float*)(ws + WS_LOGITS);
    float* part   = (float*)(ws + WS_PART);
    float* alpha  = out + 32768;

    hipLaunchKernelGGL(k_wt,         dim3(512), dim3(256), 0, stream, W_enc, Wt);
    hipLaunchKernelGGL(k_bias2,      dim3(256), dim3(256), 0, stream, dec, W_dec, b_dec, b_enc, bias2p);
    hipLaunchKernelGGL(k_logits,     dim3(512), dim3(512), 0, stream, enc, Wt, bias2p, W_full, b_full, logits);
    hipLaunchKernelGGL(k_softmax,    dim3(64),  dim3(256), 0, stream, logits, alpha);
    hipLaunchKernelGGL(k_wsum_part,  dim3(512), dim3(256), 0, stream, enc, alpha, part);
    hipLaunchKernelGGL(k_wsum_final, dim3(64),  dim3(128), 0, stream, part, out);
}

// Round 4
// 110.511 us; speedup vs baseline: 1.0211x; 1.0211x over previous
//
#include <hip/hip_runtime.h>
#include <hip/hip_bf16.h>

typedef __bf16 bf16x8 __attribute__((ext_vector_type(8)));
typedef float f32x4 __attribute__((ext_vector_type(4)));
typedef unsigned int u32;

// ws layout (bytes):
//   [0,        524288)  Wt    : bf16 W_enc^T  [N=512][K=512]
//   [524288,   655360)  bias2p: f32 [64][512]  (attn2 + b_dec + b_enc)
//   [655360,   917504)  logits: f32 [65536]
//   [917504,  1966080)  part  : f32 [64][8][512]
#define WS_WT     0
#define WS_BIAS   524288
#define WS_LOGITS 655360
#define WS_PART   917504

__device__ __forceinline__ unsigned short f2bf(float f) {
    __bf16 h = (__bf16)f;
    return __builtin_bit_cast(unsigned short, h);
}

__device__ __forceinline__ void gload_lds16(const void* g, void* l) {
    __builtin_amdgcn_global_load_lds(
        (const __attribute__((address_space(1))) u32*)g,
        (__attribute__((address_space(3))) u32*)l, 16, 0, 0);
}

// K0a: Wt[n][k] = bf16(W_enc[k][n])
__global__ void k_wt(const float* __restrict__ W, unsigned short* __restrict__ Wt) {
    int n = blockIdx.x;
    for (int k = threadIdx.x; k < 512; k += 256)
        Wt[n * 512 + k] = f2bf(W[k * 512 + n]);
}

// K0b: bias2p[b][n] = dec[b]·W_dec[:,n] + b_dec[n] + b_enc[n]
__global__ void k_bias2(const float* __restrict__ dec, const float* __restrict__ Wd,
                        const float* __restrict__ b_dec, const float* __restrict__ b_enc,
                        float* __restrict__ bias2p) {
    int blk = blockIdx.x;           // 256 blocks: b = blk>>2, nc = blk&3
    int b = blk >> 2, nc = blk & 3;
    int t = threadIdx.x;
    __shared__ float sdec[512];
    __shared__ float red[256];
    for (int k = t; k < 512; k += 256) sdec[k] = dec[b * 512 + k];
    __syncthreads();
    int n = nc * 128 + (t & 127);
    int kh = t >> 7;                // 0 or 1
    float acc = 0.f;
    int k0 = kh * 256;
    #pragma unroll 4
    for (int k = k0; k < k0 + 256; ++k)
        acc += sdec[k] * Wd[k * 512 + n];
    red[t] = acc;
    __syncthreads();
    if (t < 128) {
        int nn = nc * 128 + t;
        bias2p[b * 512 + nn] = red[t] + red[t + 128] + b_dec[nn] + b_enc[nn];
    }
}

// K1: fused enc@W_enc + bias -> relu -> ·W_full  =>  logits [B*L]
// 1024 blocks x 256 thr (4 waves). Block = 64 rows. Wave (rg,h): rg = row
// group (32 rows, two 16-row tiles), h = K-half. A half-K in regs, PINNED
// via opaque asm so the compiler cannot rematerialize the enc loads.
// Symmetric comb: each wave epilogues tile h; partner contribution via LDS.
__global__ __launch_bounds__(256, 4) void k_logits(
        const float* __restrict__ enc, const unsigned short* __restrict__ Wt,
        const float* __restrict__ bias2p, const float* __restrict__ Wf,
        float* __restrict__ logits) {
    __shared__ __align__(16) unsigned short lds[2][8192];  // 2 x 16 KB B-chunk
    __shared__ f32x4 comb[2][2][64];                       // [rg][tile][lane]

    int t = threadIdx.x;
    int lane = t & 63;
    int w = t >> 6;                 // wave 0..3
    int rg = w >> 1;                // row group 0..1
    int h = w & 1;                  // K-half
    int blk = blockIdx.x;           // 1024 blocks of 64 rows
    int b = blk >> 4;               // 16 blocks per batch
    int m = lane & 15;              // D col / staged B row
    int g = lane >> 4;              // k sub-group 0..3

    // stage chunk nc_ (16 B-rows x 1KB) into lds[bufi]; wave w stages rows w*4..+3.
    // LDS dest linear (wave-uniform base + lane*16); global src pre-swizzled lane^r.
    #define STAGE(bufi, nc_)                                                      \
        {                                                                         \
            int n0_ = (nc_) * 16;                                                 \
            _Pragma("unroll")                                                     \
            for (int j = 0; j < 4; ++j) {                                         \
                int c_ = w * 4 + j;                                               \
                const char* src_ = (const char*)Wt + (size_t)(n0_ + c_) * 1024    \
                                   + ((lane ^ c_) << 4);                          \
                gload_lds16(src_, (char*)&lds[bufi][0] + c_ * 1024);              \
            }                                                                     \
        }

    STAGE(0, 0)

    // A frags: rows blk*64 + rg*32 + {m, 16+m}, k in [h*256, h*256+256)
    bf16x8 A0[8], A1[8];
    {
        const float* ap0 = enc + (size_t)(blk * 64 + rg * 32 + m) * 512 + h * 256 + g * 8;
        const float* ap1 = ap0 + 16 * 512;
        #pragma unroll
        for (int f = 0; f < 8; ++f) {
            float4 x = *(const float4*)(ap0 + f * 32);
            float4 y = *(const float4*)(ap0 + f * 32 + 4);
            bf16x8 a;
            a[0] = (__bf16)x.x; a[1] = (__bf16)x.y; a[2] = (__bf16)x.z; a[3] = (__bf16)x.w;
            a[4] = (__bf16)y.x; a[5] = (__bf16)y.y; a[6] = (__bf16)y.z; a[7] = (__bf16)y.w;
            A0[f] = a;
            float4 x1 = *(const float4*)(ap1 + f * 32);
            float4 y1 = *(const float4*)(ap1 + f * 32 + 4);
            bf16x8 a1;
            a1[0] = (__bf16)x1.x; a1[1] = (__bf16)x1.y; a1[2] = (__bf16)x1.z; a1[3] = (__bf16)x1.w;
            a1[4] = (__bf16)y1.x; a1[5] = (__bf16)y1.y; a1[6] = (__bf16)y1.z; a1[7] = (__bf16)y1.w;
            A1[f] = a1;
        }
    }
    // Pin: make A-frag definitions opaque -> no remat, must stay in VGPRs.
    #pragma unroll
    for (int f = 0; f < 8; ++f)
        asm volatile("" : "+v"(A0[f]), "+v"(A1[f]));

    __syncthreads();                // chunk 0 staged

    float p[4] = {0.f, 0.f, 0.f, 0.f};
    int swz = m << 4;

    for (int nc = 0; nc < 32; ++nc) {
        int buf = nc & 1;
        if (nc < 31) {
            if (buf) STAGE(0, nc + 1) else STAGE(1, nc + 1)
        }
        const char* base = (const char*)&lds[buf][0] + m * 1024;
        f32x4 acc0 = {0.f, 0.f, 0.f, 0.f};
        f32x4 acc1 = {0.f, 0.f, 0.f, 0.f};
        #pragma unroll
        for (int f = 0; f < 8; ++f) {
            uint4 raw = *(const uint4*)(base + (((h * 8 + f) * 64 + g * 16) ^ swz));
            bf16x8 bfr = __builtin_bit_cast(bf16x8, raw);
            acc0 = __builtin_amdgcn_mfma_f32_16x16x32_bf16(A0[f], bfr, acc0, 0, 0, 0);
            acc1 = __builtin_amdgcn_mfma_f32_16x16x32_bf16(A1[f], bfr, acc1, 0, 0, 0);
        }
        // hand partner-tile partial to the other K-half wave
        comb[rg][h ^ 1][lane] = h ? acc0 : acc1;
        __syncthreads();
        f32x4 other = comb[rg][h][lane];
        f32x4 own = h ? acc1 : acc0;
        int col = nc * 16 + m;
        float bias = bias2p[b * 512 + col];
        float wf = Wf[col];
        #pragma unroll
        for (int r = 0; r < 4; ++r) {
            float v = own[r] + other[r] + bias;
            v = v > 0.f ? v : 0.f;
            p[r] += v * wf;
        }
        __syncthreads();            // comb reads done; staged buf complete
    }

    // wave (rg,h) owns rows blk*64 + rg*32 + h*16 + g*4 + r
    #pragma unroll
    for (int r = 0; r < 4; ++r) {
        float v = p[r];
        v += __shfl_xor(v, 1, 64);
        v += __shfl_xor(v, 2, 64);
        v += __shfl_xor(v, 4, 64);
        v += __shfl_xor(v, 8, 64);
        if (m == 0) logits[blk * 64 + rg * 32 + h * 16 + g * 4 + r] = v;
    }
}

// K2: softmax over L per batch (b_full omitted: softmax is shift-invariant)
__global__ void k_softmax(const float* __restrict__ logits, float* __restrict__ alpha) {
    int b = blockIdx.x;
    int t = threadIdx.x;
    __shared__ float red[256];
    float4 v = ((const float4*)(logits + b * 1024))[t];
    float mx = fmaxf(fmaxf(v.x, v.y), fmaxf(v.z, v.w));
    red[t] = mx;
    __syncthreads();
    for (int s = 128; s > 0; s >>= 1) {
        if (t < s) red[t] = fmaxf(red[t], red[t + s]);
        __syncthreads();
    }
    mx = red[0];
    __syncthreads();
    float4 e;
    e.x = expf(v.x - mx); e.y = expf(v.y - mx);
    e.z = expf(v.z - mx); e.w = expf(v.w - mx);
    red[t] = e.x + e.y + e.z + e.w;
    __syncthreads();
    for (int s = 128; s > 0; s >>= 1) {
        if (t < s) red[t] += red[t + s];
        __syncthreads();
    }
    float inv = 1.0f / red[0];
    float4 o;
    o.x = e.x * inv; o.y = e.y * inv; o.z = e.z * inv; o.w = e.w * inv;
    ((float4*)(alpha + b * 1024))[t] = o;
}

// K3: partial weighted sums over l-chunks of 128 (float4 loads, 16B/lane)
__global__ void k_wsum_part(const float* __restrict__ enc, const float* __restrict__ alpha,
                            float* __restrict__ part) {
    int blk = blockIdx.x;           // 512 blocks: b = blk>>3, chunk c = blk&7
    int b = blk >> 3, c = blk & 7;
    int t = threadIdx.x;
    int col = (t & 127) * 4;
    int lh = t >> 7;                // 0/1: which l-parity
    const float* ep = enc + (size_t)(b * 1024 + c * 128) * 512;
    const float* al = alpha + b * 1024 + c * 128;
    float4 s = {0.f, 0.f, 0.f, 0.f};
    #pragma unroll 4
    for (int i = 0; i < 64; ++i) {
        int l = i * 2 + lh;
        float a = al[l];
        float4 e = *(const float4*)(ep + (size_t)l * 512 + col);
        s.x += e.x * a; s.y += e.y * a; s.z += e.z * a; s.w += e.w * a;
    }
    __shared__ float red[2][512];
    *(float4*)&red[lh][col] = s;
    __syncthreads();
    if (t < 128) {
        float4 a0 = *(const float4*)&red[0][t * 4];
        float4 a1 = *(const float4*)&red[1][t * 4];
        float4 o;
        o.x = a0.x + a1.x; o.y = a0.y + a1.y;
        o.z = a0.z + a1.z; o.w = a0.w + a1.w;
        *(float4*)(part + (size_t)blk * 512 + t * 4) = o;
    }
}

// K4: reduce 8 partials -> attn_weighted_enc (128 thr, float4)
__global__ void k_wsum_final(const float* __restrict__ part, float* __restrict__ out) {
    int b = blockIdx.x;
    int t = threadIdx.x;
    float4 s = {0.f, 0.f, 0.f, 0.f};
    #pragma unroll
    for (int c = 0; c < 8; ++c) {
        float4 v = *(const float4*)(part + (size_t)(b * 8 + c) * 512 + t * 4);
        s.x += v.x; s.y += v.y; s.z += v.z; s.w += v.w;
    }
    *(float4*)(out + b * 512 + t * 4) = s;
}

extern "C" void kernel_launch(void* const* d_in, const int* in_sizes, int n_in,
                              void* d_out, int out_size, void* d_ws, size_t ws_size,
                              hipStream_t stream) {
    const float* enc    = (const float*)d_in[0];  // [64,1024,512]
    const float* dec    = (const float*)d_in[1];  // [64,512]
    const float* W_enc  = (const float*)d_in[2];  // [512,512]
    const float* b_enc  = (const float*)d_in[3];  // [512]
    const float* W_dec  = (const float*)d_in[4];  // [512,512]
    const float* b_dec  = (const float*)d_in[5];  // [512]
    const float* W_full = (const float*)d_in[6];  // [512]
    // d_in[7] = b_full: unused (softmax is shift-invariant)

    float* out = (float*)d_out;                   // [0,32768) weighted enc; [32768,98304) alpha
    char* ws = (char*)d_ws;
    unsigned short* Wt = (unsigned short*)(ws + WS_WT);
    float* bias2p = (float*)(ws + WS_BIAS);
    float* logits = (float*)(ws + WS_LOGITS);
    float* part   = (float*)(ws + WS_PART);
    float* alpha  = out + 32768;

    hipLaunchKernelGGL(k_wt,         dim3(512),  dim3(256), 0, stream, W_enc, Wt);
    hipLaunchKernelGGL(k_bias2,      dim3(256),  dim3(256), 0, stream, dec, W_dec, b_dec, b_enc, bias2p);
    hipLaunchKernelGGL(k_logits,     dim3(1024), dim3(256), 0, stream, enc, Wt, bias2p, W_full, logits);
    hipLaunchKernelGGL(k_softmax,    dim3(64),   dim3(256), 0, stream, logits, alpha);
    hipLaunchKernelGGL(k_wsum_part,  dim3(512),  dim3(256), 0, stream, enc, alpha, part);
    hipLaunchKernelGGL(k_wsum_final, dim3(64),   dim3(128), 0, stream, part, out);
}